// Round 6
// baseline (322.633 us; speedup 1.0000x reference)
//
#include <hip/hip_runtime.h>

// out[i,j] = (z[i,:] . w) * w[j] + bias[j], all f32.  S=65536, B=1024.
// Wave-role-split pipelined kernel: 256 blocks x 512 threads, 4 rows/block.
//   phase 0:        all 8 waves: dot(z[r0])
//   phase p=1..3:   waves 0-3 dot(z[r0+p])  ||  waves 4-7 NT-store out[r0+p-1]
//   final:          all 8 waves: NT-store out[r0+3]
// Key fix vs R5: vmcnt decrements IN ORDER, so a wave that interleaves NT
// stores with loads stalls its loads on store completion. Here each wave has a
// homogeneous stream (readers: loads only; writers: L2-hit loads + NT stores),
// while the HBM system still sees blended read+write traffic across waves.

#define SDIM  65536
#define S4    16384      // float4 per row
#define BLK   512
#define NROWS 4

typedef float floatx4 __attribute__((ext_vector_type(4)));

__device__ __forceinline__ float dot4(floatx4 a, floatx4 b) {
    return a.x * b.x + a.y * b.y + a.z * b.z + a.w * b.w;
}

__device__ __forceinline__ float wave_reduce(float v) {
    #pragma unroll
    for (int off = 32; off > 0; off >>= 1)
        v += __shfl_down(v, off, 64);
    return v;
}

// Dot over a per-wave segment of NF4 float4, lane-strided by 64, unroll 8:
// 16 loads in flight per lane, 8 independent accumulator chains.
template<int NF4>
__device__ __forceinline__ float dot_seg(const floatx4* __restrict__ zs,
                                         const floatx4* __restrict__ ws,
                                         int lane)
{
    float a0 = 0.f, a1 = 0.f, a2 = 0.f, a3 = 0.f;
    float a4 = 0.f, a5 = 0.f, a6 = 0.f, a7 = 0.f;
    #pragma unroll
    for (int g = 0; g < NF4 / (8 * 64); ++g) {
        const int i = g * 8 * 64 + lane;
        floatx4 x0 = zs[i];       floatx4 x1 = zs[i + 64];
        floatx4 x2 = zs[i + 128]; floatx4 x3 = zs[i + 192];
        floatx4 x4 = zs[i + 256]; floatx4 x5 = zs[i + 320];
        floatx4 x6 = zs[i + 384]; floatx4 x7 = zs[i + 448];
        floatx4 y0 = ws[i];       floatx4 y1 = ws[i + 64];
        floatx4 y2 = ws[i + 128]; floatx4 y3 = ws[i + 192];
        floatx4 y4 = ws[i + 256]; floatx4 y5 = ws[i + 320];
        floatx4 y6 = ws[i + 384]; floatx4 y7 = ws[i + 448];
        a0 += dot4(x0, y0); a1 += dot4(x1, y1);
        a2 += dot4(x2, y2); a3 += dot4(x3, y3);
        a4 += dot4(x4, y4); a5 += dot4(x5, y5);
        a6 += dot4(x6, y6); a7 += dot4(x7, y7);
    }
    return ((a0 + a1) + (a2 + a3)) + ((a4 + a5) + (a6 + a7));
}

// NT-store a per-wave segment: out = s*w + bias. Loads (L2-hit) are issued
// before the dependent stores; stores are fire-and-forget.
template<int NF4>
__device__ __forceinline__ void store_seg(floatx4* __restrict__ os,
                                          const floatx4* __restrict__ ws,
                                          const floatx4* __restrict__ bs,
                                          float s, int lane)
{
    #pragma unroll
    for (int g = 0; g < NF4 / (4 * 64); ++g) {
        const int i = g * 4 * 64 + lane;
        floatx4 y0 = ws[i];       floatx4 y1 = ws[i + 64];
        floatx4 y2 = ws[i + 128]; floatx4 y3 = ws[i + 192];
        floatx4 c0 = bs[i];       floatx4 c1 = bs[i + 64];
        floatx4 c2 = bs[i + 128]; floatx4 c3 = bs[i + 192];
        floatx4 r0, r1, r2, r3;
        r0.x = fmaf(s, y0.x, c0.x); r0.y = fmaf(s, y0.y, c0.y);
        r0.z = fmaf(s, y0.z, c0.z); r0.w = fmaf(s, y0.w, c0.w);
        r1.x = fmaf(s, y1.x, c1.x); r1.y = fmaf(s, y1.y, c1.y);
        r1.z = fmaf(s, y1.z, c1.z); r1.w = fmaf(s, y1.w, c1.w);
        r2.x = fmaf(s, y2.x, c2.x); r2.y = fmaf(s, y2.y, c2.y);
        r2.z = fmaf(s, y2.z, c2.z); r2.w = fmaf(s, y2.w, c2.w);
        r3.x = fmaf(s, y3.x, c3.x); r3.y = fmaf(s, y3.y, c3.y);
        r3.z = fmaf(s, y3.z, c3.z); r3.w = fmaf(s, y3.w, c3.w);
        __builtin_nontemporal_store(r0, &os[i]);
        __builtin_nontemporal_store(r1, &os[i + 64]);
        __builtin_nontemporal_store(r2, &os[i + 128]);
        __builtin_nontemporal_store(r3, &os[i + 192]);
    }
}

__global__ __launch_bounds__(BLK) void pipe_rolesplit_kernel(
    const float* __restrict__ z,
    const float* __restrict__ w,
    const float* __restrict__ bias,
    float* __restrict__ out)
{
    const int wid  = threadIdx.x >> 6;   // 0..7
    const int lane = threadIdx.x & 63;
    const int r0   = blockIdx.x * NROWS;

    const floatx4* __restrict__ w4 = reinterpret_cast<const floatx4*>(w);
    const floatx4* __restrict__ b4 = reinterpret_cast<const floatx4*>(bias);

    __shared__ float s_red[8];
    __shared__ float s_bcast[NROWS];

    // ---- phase 0: all 8 waves dot row r0 (2048 f4 per wave) ----
    {
        const floatx4* zr =
            reinterpret_cast<const floatx4*>(z + (size_t)r0 * SDIM);
        float acc = dot_seg<2048>(zr + wid * 2048, w4 + wid * 2048, lane);
        acc = wave_reduce(acc);
        if (lane == 0) s_red[wid] = acc;
        __syncthreads();
        if (threadIdx.x == 0) {
            float t = 0.f;
            #pragma unroll
            for (int i = 0; i < 8; ++i) t += s_red[i];
            s_bcast[0] = t;
        }
        __syncthreads();
    }

    // ---- phases 1..NROWS-1: readers dot row r0+p, writers store row r0+p-1 ----
    #pragma unroll
    for (int p = 1; p < NROWS; ++p) {
        if (wid < 4) {
            const floatx4* zr =
                reinterpret_cast<const floatx4*>(z + (size_t)(r0 + p) * SDIM);
            float acc = dot_seg<4096>(zr + wid * 4096, w4 + wid * 4096, lane);
            acc = wave_reduce(acc);
            if (lane == 0) s_red[wid] = acc;
        } else {
            const int wj = wid - 4;
            floatx4* orow =
                reinterpret_cast<floatx4*>(out + (size_t)(r0 + p - 1) * SDIM);
            store_seg<4096>(orow + wj * 4096, w4 + wj * 4096, b4 + wj * 4096,
                            s_bcast[p - 1], lane);
        }
        __syncthreads();
        if (threadIdx.x == 0)
            s_bcast[p] = (s_red[0] + s_red[1]) + (s_red[2] + s_red[3]);
        __syncthreads();
    }

    // ---- final: all 8 waves store row r0+NROWS-1 ----
    {
        floatx4* orow =
            reinterpret_cast<floatx4*>(out + (size_t)(r0 + NROWS - 1) * SDIM);
        store_seg<2048>(orow + wid * 2048, w4 + wid * 2048, b4 + wid * 2048,
                        s_bcast[NROWS - 1], lane);
    }
}

extern "C" void kernel_launch(void* const* d_in, const int* in_sizes, int n_in,
                              void* d_out, int out_size, void* d_ws, size_t ws_size,
                              hipStream_t stream)
{
    const float* z    = (const float*)d_in[0];
    const float* w    = (const float*)d_in[1];  // (1,S,1) flat == (S,)
    const float* bias = (const float*)d_in[2];
    float* out = (float*)d_out;

    const int B = in_sizes[0] / SDIM;           // 1024

    pipe_rolesplit_kernel<<<B / NROWS, BLK, 0, stream>>>(z, w, bias, out);
}

// Round 7
// 105.470 us; speedup vs baseline: 3.0590x; 3.0590x over previous
//
#include <hip/hip_runtime.h>

// out[i,j] = (z[i,:] . w) * w[j] + bias[j], all f32.  S=65536, B=1024.
// Fused, one row per block (no cross-row deps): dot(z[row],w) -> reduce ->
// NT-store out[row]. This is R2's structure with R4's ILP fix: unroll-4,
// 4 accumulator chains, 8 loads in flight (R2 failed only because VGPR=20 /
// 2 loads in flight starved MLP). VGPR must stay <=64 so all 1024 blocks
// (512 thr, 4 blocks/CU) are co-resident.

#define SDIM 65536
#define S4   16384     // float4 per row
#define BLK  512

typedef float floatx4 __attribute__((ext_vector_type(4)));

__global__ __launch_bounds__(BLK) void fused_ilp_kernel(
    const float* __restrict__ z,
    const float* __restrict__ w,
    const float* __restrict__ bias,
    float* __restrict__ out)
{
    const int row = blockIdx.x;
    const floatx4* __restrict__ zrow =
        reinterpret_cast<const floatx4*>(z + (size_t)row * SDIM);
    const floatx4* __restrict__ w4 = reinterpret_cast<const floatx4*>(w);
    const floatx4* __restrict__ b4 = reinterpret_cast<const floatx4*>(bias);
    floatx4* __restrict__ orow =
        reinterpret_cast<floatx4*>(out + (size_t)row * SDIM);

    // ---- phase 1: dot, unroll 4, 8 loads in flight, 4 accum chains ----
    float a0 = 0.f, a1 = 0.f, a2 = 0.f, a3 = 0.f;
    for (int i = threadIdx.x; i < S4; i += 4 * BLK) {
        floatx4 x0 = zrow[i];
        floatx4 x1 = zrow[i + BLK];
        floatx4 x2 = zrow[i + 2 * BLK];
        floatx4 x3 = zrow[i + 3 * BLK];
        floatx4 y0 = w4[i];
        floatx4 y1 = w4[i + BLK];
        floatx4 y2 = w4[i + 2 * BLK];
        floatx4 y3 = w4[i + 3 * BLK];
        a0 += x0.x * y0.x + x0.y * y0.y + x0.z * y0.z + x0.w * y0.w;
        a1 += x1.x * y1.x + x1.y * y1.y + x1.z * y1.z + x1.w * y1.w;
        a2 += x2.x * y2.x + x2.y * y2.y + x2.z * y2.z + x2.w * y2.w;
        a3 += x3.x * y3.x + x3.y * y3.y + x3.z * y3.z + x3.w * y3.w;
    }
    float acc = (a0 + a1) + (a2 + a3);

    #pragma unroll
    for (int off = 32; off > 0; off >>= 1)
        acc += __shfl_down(acc, off, 64);

    __shared__ float smem[BLK / 64];
    __shared__ float s_bcast;
    const int lane = threadIdx.x & 63;
    const int wid  = threadIdx.x >> 6;
    if (lane == 0) smem[wid] = acc;
    __syncthreads();
    if (threadIdx.x == 0) {
        float t = 0.f;
        #pragma unroll
        for (int i = 0; i < BLK / 64; ++i) t += smem[i];
        s_bcast = t;
    }
    __syncthreads();
    const float s = s_bcast;

    // ---- phase 2: out[row,:] = s*w + bias, unroll 4, NT stores ----
    for (int i = threadIdx.x; i < S4; i += 4 * BLK) {
        floatx4 y0 = w4[i];
        floatx4 y1 = w4[i + BLK];
        floatx4 y2 = w4[i + 2 * BLK];
        floatx4 y3 = w4[i + 3 * BLK];
        floatx4 c0 = b4[i];
        floatx4 c1 = b4[i + BLK];
        floatx4 c2 = b4[i + 2 * BLK];
        floatx4 c3 = b4[i + 3 * BLK];
        floatx4 r0, r1, r2, r3;
        r0.x = fmaf(s, y0.x, c0.x); r0.y = fmaf(s, y0.y, c0.y);
        r0.z = fmaf(s, y0.z, c0.z); r0.w = fmaf(s, y0.w, c0.w);
        r1.x = fmaf(s, y1.x, c1.x); r1.y = fmaf(s, y1.y, c1.y);
        r1.z = fmaf(s, y1.z, c1.z); r1.w = fmaf(s, y1.w, c1.w);
        r2.x = fmaf(s, y2.x, c2.x); r2.y = fmaf(s, y2.y, c2.y);
        r2.z = fmaf(s, y2.z, c2.z); r2.w = fmaf(s, y2.w, c2.w);
        r3.x = fmaf(s, y3.x, c3.x); r3.y = fmaf(s, y3.y, c3.y);
        r3.z = fmaf(s, y3.z, c3.z); r3.w = fmaf(s, y3.w, c3.w);
        __builtin_nontemporal_store(r0, &orow[i]);
        __builtin_nontemporal_store(r1, &orow[i + BLK]);
        __builtin_nontemporal_store(r2, &orow[i + 2 * BLK]);
        __builtin_nontemporal_store(r3, &orow[i + 3 * BLK]);
    }
}

extern "C" void kernel_launch(void* const* d_in, const int* in_sizes, int n_in,
                              void* d_out, int out_size, void* d_ws, size_t ws_size,
                              hipStream_t stream)
{
    const float* z    = (const float*)d_in[0];
    const float* w    = (const float*)d_in[1];  // (1,S,1) flat == (S,)
    const float* bias = (const float*)d_in[2];
    float* out = (float*)d_out;

    const int B = in_sizes[0] / SDIM;           // 1024

    fused_ilp_kernel<<<B, BLK, 0, stream>>>(z, w, bias, out);
}